// Round 6
// baseline (1307.609 us; speedup 1.0000x reference)
//
#include <hip/hip_runtime.h>
#include <hip/hip_bf16.h>

#define N_NODES 100000
#define S_SAMP 2
#define G_GRAPH 8
#define E_EDGES 400000
#define NLAYER 4
#define IN_CH 265
#define KBASE 256                       // s-invariant features: 223 padded to 256
#define MT128 ((N_NODES + 127) / 128)   // 782 row tiles (128 rows)
#define NPAD (MT128 * 128)              // 100096 padded rows
#define NG128 ((MT128 + 7) / 8)         // 98 groups -> 8 XCDs
#define NB1 ((N_NODES + 1023) / 1024)   // 98 scan blocks

typedef unsigned short u16;
typedef unsigned int u32;
typedef short bf16x8 __attribute__((ext_vector_type(8)));
typedef float f32x4 __attribute__((ext_vector_type(4)));

__device__ __forceinline__ float b2f(u16 u) {
    union { u32 i; float f; } x; x.i = ((u32)u) << 16; return x.f;
}
__device__ __forceinline__ u16 f2b(float f) {
    __hip_bfloat16 h = __float2bfloat16(f);
    return *reinterpret_cast<u16*>(&h);
}

// async global->LDS, 16B per lane; lds dest = wave-uniform base + lane*16
__device__ __forceinline__ void gl_lds16(const u16* g, u16* l) {
    __builtin_amdgcn_global_load_lds(
        (const __attribute__((address_space(1))) void*)g,
        (__attribute__((address_space(3))) void*)l, 16, 0, 0);
}

// ---------------------------------------------------------------- base features (s-invariant)
// xb[n][256] = [x(53)|op(32)|dim(138)|pad(33)]; 64 threads/node, ushort4 stores
__global__ __launch_bounds__(256) void build_base_k(const float* __restrict__ xf,
                                                    const float* __restrict__ dimf,
                                                    const float* __restrict__ opemb,
                                                    const int* __restrict__ opcode,
                                                    u16* __restrict__ xb) {
    int item = blockIdx.x * blockDim.x + threadIdx.x;
    int n = item >> 6;
    if (n >= N_NODES) return;
    int base = (item & 63) * 4;
    int opc = opcode[n];
    ushort4 o;
    u16* op = &o.x;
    #pragma unroll
    for (int u = 0; u < 4; u++) {
        int c = base + u;
        float v = 0.0f;
        if (c < 53)       v = xf[(size_t)n * 53 + c];
        else if (c < 85)  v = opemb[opc * 32 + (c - 53)];
        else if (c < 223) v = dimf[(size_t)n * 138 + (c - 85)];
        op[u] = f2b(v);
    }
    *(ushort4*)(xb + (size_t)n * KBASE + base) = o;
}

// ---------------------------------------------------------------- weight packing
// Wt: [L][512][256] bf16 transposed.  col<256 -> Wr_cat (P), col>=256 -> Wl_cat (H).
__global__ void pack_w_k(const float* __restrict__ cWl, const float* __restrict__ rWl,
                         const float* __restrict__ cWr, const float* __restrict__ rWr,
                         const float* __restrict__ cb,  const float* __restrict__ rb,
                         u16* __restrict__ Wt, float* __restrict__ bcat) {
    int idx = blockIdx.x * blockDim.x + threadIdx.x;
    if (idx < NLAYER * 512 * 256) {
        int l = idx >> 17;
        int r = idx & 131071;
        int j = r >> 8;
        int k = r & 255;
        int jj = j & 255;
        int half = j >> 8;
        int sub = jj >> 7;
        int col = jj & 127;
        const float* src = half ? (sub ? rWl : cWl) : (sub ? rWr : cWr);
        Wt[idx] = f2b(src[((size_t)l * 256 + k) * 128 + col]);
    }
    if (idx < NLAYER * 512) {
        int l = idx >> 9;
        int j = idx & 511;
        float v = 0.0f;
        if (j < 256) v = (j < 128) ? cb[l * 128 + j] : rb[l * 128 + (j - 128)];
        bcat[idx] = v;
    }
}

// preWt [256 out][256 k] transposed; only k<223 (base features), rest zero
__global__ void pack_pre_k(const float* __restrict__ preW, u16* __restrict__ preWt) {
    int idx = blockIdx.x * blockDim.x + threadIdx.x;
    if (idx >= 256 * KBASE) return;
    int j = idx >> 8;
    int k = idx & 255;
    preWt[idx] = (k < 223) ? f2b(preW[(size_t)k * 256 + j]) : (u16)0;
}

// tvec[g][s][c] = sum_k tile_feat[g][s][k] * preW[247+k][c]  (16 x 256, fp32)
__global__ void tvec_k(const float* __restrict__ tilef, const float* __restrict__ preW,
                       float* __restrict__ tvec) {
    int idx = blockIdx.x * blockDim.x + threadIdx.x;
    if (idx >= G_GRAPH * S_SAMP * 256) return;
    int c = idx & 255;
    int gs = idx >> 8;
    float a = 0.0f;
    #pragma unroll
    for (int k = 0; k < 18; k++)
        a += tilef[gs * 18 + k] * preW[(size_t)(247 + k) * 256 + c];
    tvec[idx] = a;
}

// ---------------------------------------------------------------- degrees + CSR
__global__ void deg_k(const int* __restrict__ ei, int* __restrict__ degF,
                      int* __restrict__ degR) {
    int e = blockIdx.x * blockDim.x + threadIdx.x;
    if (e < E_EDGES) {
        atomicAdd(&degF[ei[E_EDGES + e]], 1);
        atomicAdd(&degR[ei[e]], 1);
    }
}

__global__ __launch_bounds__(1024) void scan1_k(const int* __restrict__ degF,
                                                const int* __restrict__ degR,
                                                int* __restrict__ rpF,
                                                int* __restrict__ rpR,
                                                int* __restrict__ bsum) {
    const int* deg = blockIdx.y ? degR : degF;
    int* rp = blockIdx.y ? rpR : rpF;
    __shared__ int buf[1024];
    int i = blockIdx.x * 1024 + threadIdx.x;
    int v = (i < N_NODES) ? deg[i] : 0;
    buf[threadIdx.x] = v;
    __syncthreads();
    for (int off = 1; off < 1024; off <<= 1) {
        int t = (threadIdx.x >= off) ? buf[threadIdx.x - off] : 0;
        __syncthreads();
        buf[threadIdx.x] += t;
        __syncthreads();
    }
    if (i < N_NODES) rp[i] = buf[threadIdx.x] - v;
    if (threadIdx.x == 1023) bsum[blockIdx.y * NB1 + blockIdx.x] = buf[1023];
}

__global__ __launch_bounds__(256) void scan2_k(int* __restrict__ bsum,
                                               int* __restrict__ rpF,
                                               int* __restrict__ rpR) {
    __shared__ int buf[2][128];
    int half = threadIdx.x >> 7;
    int t = threadIdx.x & 127;
    int v = (t < NB1) ? bsum[half * NB1 + t] : 0;
    buf[half][t] = v;
    __syncthreads();
    for (int off = 1; off < 128; off <<= 1) {
        int x = (t >= off) ? buf[half][t - off] : 0;
        __syncthreads();
        buf[half][t] += x;
        __syncthreads();
    }
    if (t < NB1) bsum[half * NB1 + t] = buf[half][t] - v;
    if (t == NB1) (half ? rpR : rpF)[N_NODES] = buf[half][NB1 - 1];
}

__global__ void scan3_k(const int* __restrict__ bsum, int* __restrict__ rpF,
                        int* __restrict__ rpR) {
    int* rp = blockIdx.y ? rpR : rpF;
    int i = blockIdx.x * 1024 + threadIdx.x;
    if (i < N_NODES) rp[i] += bsum[blockIdx.y * NB1 + blockIdx.x];
}

__global__ void inv_cursor_k(const int* __restrict__ degF, const int* __restrict__ degR,
                             const int* __restrict__ rpF, const int* __restrict__ rpR,
                             float* __restrict__ invF, float* __restrict__ invR,
                             int* __restrict__ curF, int* __restrict__ curR) {
    int i = blockIdx.x * blockDim.x + threadIdx.x;
    if (i < N_NODES) {
        invF[i] = 1.0f / fmaxf((float)degF[i], 1.0f);
        invR[i] = 1.0f / fmaxf((float)degR[i], 1.0f);
        curF[i] = rpF[i];
        curR[i] = rpR[i];
    }
}

__global__ void fill_k(const int* __restrict__ ei, int* __restrict__ curF,
                       int* __restrict__ curR, int* __restrict__ colF,
                       int* __restrict__ colR) {
    int e = blockIdx.x * blockDim.x + threadIdx.x;
    if (e < E_EDGES) {
        int s = ei[e], t = ei[E_EDGES + e];
        colF[atomicAdd(&curF[t], 1)] = s;
        colR[atomicAdd(&curR[s], 1)] = t;
    }
}

// ---------------------------------------------------------------- MFMA GEMM (128x128 tile, DMA-staged)
// ROUND-6: tile widened 64->128 cols. Per chunk per wave: 16 DMA, 64 MFMA
// (vs round-4's 12 DMA / 32 MFMA) -- 2x compute per barrier-drain hides the
// same ~500-900cy staging latency; A-tile L2 re-reads halve. LDS 64 KB
// (As 32 + Bs 32) -> 2 blocks/CU. Round-2 lesson (less compute per drain
// REGRESSED) motivates this inverse. C^T epilogue (round-4, verified):
// swapped MFMA operands -> 4 consecutive C-cols per f32x4 -> ushort4 stores.
// Global col<256 -> C0 (+bias), else C1. XCD swizzle: bid = g*(8*COLT)+c*8+x.
template <bool RELU_OUT, int NCHUNK, int COLT>
__global__ __launch_bounds__(256) void mmB_k(const u16* __restrict__ A,
                                             const u16* __restrict__ Bt,
                                             const float* __restrict__ bias,
                                             u16* __restrict__ C0,
                                             u16* __restrict__ C1,
                                             int M) {
    __shared__ u16 As[128 * 128];    // 32 KB
    __shared__ u16 Bs[128 * 128];    // 32 KB
    constexpr int K = NCHUNK * 128;

    int bid = blockIdx.x;
    int x = bid & 7;
    int q = bid >> 3;
    int c = q % COLT;
    int g = q / COLT;
    int rowTile = g * 8 + x;
    if (rowTile >= MT128) return;
    int rowBase = rowTile * 128;
    int colBase = c * 128;

    int tid = threadIdx.x;
    int wv = tid >> 6;
    int lane = tid & 63;
    int quad = lane >> 4;
    int l16 = lane & 15;
    int rsub = lane >> 4;
    int sl = lane & 15;

    f32x4 acc[2][8] = {};

    for (int ci = 0; ci < NCHUNK; ci++) {
        int k0 = ci * 128;
        // A: wave wv stages rows [wv*32, wv*32+32): 8 DMA instrs x 4 rows
        #pragma unroll
        for (int i = 0; i < 8; i++) {
            int r = wv * 32 + 4 * i + rsub;
            int ch = sl ^ (r & 15);
            gl_lds16(A + (size_t)(rowBase + r) * K + k0 + ch * 8,
                     As + (wv * 32 + 4 * i) * 128);
        }
        // B: wave wv stages rows [wv*32, wv*32+32): 8 DMA instrs
        #pragma unroll
        for (int i = 0; i < 8; i++) {
            int r = wv * 32 + 4 * i + rsub;
            int ch = sl ^ (r & 15);
            gl_lds16(Bt + (size_t)(colBase + r) * K + k0 + ch * 8,
                     Bs + (wv * 32 + 4 * i) * 128);
        }
        __syncthreads();
        #pragma unroll
        for (int ks = 0; ks < 4; ks++) {
            int ca = ks * 4 + quad;
            bf16x8 af[2];
            #pragma unroll
            for (int rf = 0; rf < 2; rf++) {
                int ra = wv * 32 + rf * 16 + l16;
                af[rf] = *(const bf16x8*)(As + ra * 128 + (ca ^ (ra & 15)) * 8);
            }
            #pragma unroll
            for (int cf = 0; cf < 8; cf++) {
                int rb = cf * 16 + l16;
                bf16x8 bf = *(const bf16x8*)(Bs + rb * 128 + (ca ^ (rb & 15)) * 8);
                // swapped operands: acc = (A.B)^T fragment (round-4, verified)
                acc[0][cf] = __builtin_amdgcn_mfma_f32_16x16x32_bf16(bf, af[0], acc[0][cf], 0, 0, 0);
                acc[1][cf] = __builtin_amdgcn_mfma_f32_16x16x32_bf16(bf, af[1], acc[1][cf], 0, 0, 0);
            }
        }
        if (ci + 1 < NCHUNK) __syncthreads();
    }

    // epilogue (C^T frag): C-row = l16, C-col = quad*4 + r (4 consecutive cols)
    u16* dst = (colBase < 256) ? C0 : C1;
    int cb = colBase & 255;
    #pragma unroll
    for (int rf = 0; rf < 2; rf++) {
        int row = rowBase + wv * 32 + rf * 16 + l16;
        if (row < M) {
            #pragma unroll
            for (int cf = 0; cf < 8; cf++) {
                int colr = cf * 16 + quad * 4;
                float4 bv4 = *(const float4*)(bias + colBase + colr);
                float v0 = acc[rf][cf][0] + bv4.x;
                float v1 = acc[rf][cf][1] + bv4.y;
                float v2 = acc[rf][cf][2] + bv4.z;
                float v3 = acc[rf][cf][3] + bv4.w;
                if (RELU_OUT) {
                    v0 = fmaxf(v0, 0.0f); v1 = fmaxf(v1, 0.0f);
                    v2 = fmaxf(v2, 0.0f); v3 = fmaxf(v3, 0.0f);
                }
                ushort4 o;
                o.x = f2b(v0); o.y = f2b(v1); o.z = f2b(v2); o.w = f2b(v3);
                *(ushort4*)(dst + (size_t)row * 256 + cb + colr) = o;
            }
        }
    }
}

// ---------------------------------------------------------------- per-s pre-layer fixup
// X0[n] = relu(Xmid[n] + lay[n,s](24) @ Wlay(24x256) + tvec[batch[n],s])
// ROUND-6: W in LDS (24 KB) -- rounds 4/5 proved the compiler will NOT keep
// W[24] in VGPRs (sinks the loop-invariant loads; asm-pin failed too).
// Each wave processes 4 NODES per W-read to amortize LDS traffic 4x
// (0.6 GB/dispatch ~ 9us) ; VALU ~8us ; HBM 88 MB ~14us -> ~22us target.
__global__ __launch_bounds__(256) void pre_fix_k(const u16* __restrict__ Xmid,
                                                 const float* __restrict__ layf,
                                                 const float* __restrict__ preW,
                                                 const float* __restrict__ tvec,
                                                 const int* __restrict__ batch,
                                                 int s, u16* __restrict__ X0) {
    __shared__ float Ws[24 * 256];       // 24 KB
    __shared__ float tv[G_GRAPH * 256];  // 8 KB
    for (int i = threadIdx.x; i < 24 * 256; i += 256) {
        int k = i >> 8, c = i & 255;
        Ws[i] = preW[(size_t)(223 + k) * 256 + c];
    }
    for (int i = threadIdx.x; i < G_GRAPH * 256; i += 256) {
        int g = i >> 8, c = i & 255;
        tv[i] = tvec[(g * S_SAMP + s) * 256 + c];
    }
    __syncthreads();

    int wv = threadIdx.x >> 6;
    int lane = threadIdx.x & 63;
    int c0 = lane * 4;

    // wave handles 4 consecutive nodes per iteration
    for (int nb = (blockIdx.x * 4 + wv) * 4; nb < N_NODES; nb += gridDim.x * 16) {
        int nc[4];
        float4 acc[4];
        const float4* lp[4];
        #pragma unroll
        for (int ii = 0; ii < 4; ii++) {
            int n = nb + ii;
            nc[ii] = (n < N_NODES) ? n : (N_NODES - 1);   // clamp for safe loads
            int g = batch[nc[ii]];
            acc[ii] = *(const float4*)&tv[g * 256 + c0];
            lp[ii] = (const float4*)(layf + ((size_t)nc[ii] * S_SAMP + s) * 24);
        }
        #pragma unroll
        for (int qg = 0; qg < 6; qg++) {
            float4 Lq[4];
            #pragma unroll
            for (int ii = 0; ii < 4; ii++) Lq[ii] = lp[ii][qg];
            #pragma unroll
            for (int kk = 0; kk < 4; kk++) {
                float4 wk = *(const float4*)&Ws[(qg * 4 + kk) * 256 + c0];
                #pragma unroll
                for (int ii = 0; ii < 4; ii++) {
                    float lv = (kk == 0) ? Lq[ii].x : (kk == 1) ? Lq[ii].y
                             : (kk == 2) ? Lq[ii].z : Lq[ii].w;
                    acc[ii].x += lv * wk.x;
                    acc[ii].y += lv * wk.y;
                    acc[ii].z += lv * wk.z;
                    acc[ii].w += lv * wk.w;
                }
            }
        }
        #pragma unroll
        for (int ii = 0; ii < 4; ii++) {
            if (nb + ii < N_NODES) {
                ushort4 m = *(const ushort4*)(Xmid + (size_t)nc[ii] * 256 + c0);
                ushort4 o;
                o.x = f2b(fmaxf(b2f(m.x) + acc[ii].x, 0.0f));
                o.y = f2b(fmaxf(b2f(m.y) + acc[ii].y, 0.0f));
                o.z = f2b(fmaxf(b2f(m.z) + acc[ii].z, 0.0f));
                o.w = f2b(fmaxf(b2f(m.w) + acc[ii].w, 0.0f));
                *(ushort4*)(X0 + (size_t)nc[ii] * 256 + c0) = o;
            }
        }
    }
}

// ---------------------------------------------------------------- aggregation (CSR gather)
// One wave per node. Lanes 0-31: fwd half (H[.,0:128]); lanes 32-63: rev half.
// X := relu(X + inv*gather). If DOT: dotbuf[n] = X_new . w.
template <bool DOT>
__global__ __launch_bounds__(256) void agg_k(const int* __restrict__ rpF,
                                             const int* __restrict__ colF,
                                             const int* __restrict__ rpR,
                                             const int* __restrict__ colR,
                                             const float* __restrict__ invF,
                                             const float* __restrict__ invR,
                                             const u16* __restrict__ H,
                                             u16* __restrict__ Xn,
                                             const float* __restrict__ w,
                                             float* __restrict__ dotbuf) {
    int n = (blockIdx.x * blockDim.x + threadIdx.x) >> 6;
    if (n >= N_NODES) return;
    int lane = threadIdx.x & 63;
    int half = lane >> 5;
    int l32 = lane & 31;
    const int* rp  = half ? rpR : rpF;
    const int* col = half ? colR : colF;
    float inv = half ? invR[n] : invF[n];
    const u16* Hb = H + half * 128 + 4 * l32;

    // early loads: X row and head-w overlap the gather latency
    u16* xp = Xn + (size_t)n * 256 + 4 * lane;
    ushort4 xv = *(const ushort4*)xp;
    float4 wv4 = DOT ? *(const float4*)(w + 4 * lane) : float4{0, 0, 0, 0};

    float a0 = 0, a1 = 0, a2 = 0, a3 = 0;
    int b = rp[n], e = rp[n + 1];
    int j = b;
    for (; j + 7 < e; j += 8) {
        int c0 = col[j],     c1 = col[j + 1], c2 = col[j + 2], c3 = col[j + 3];
        int c4 = col[j + 4], c5 = col[j + 5], c6 = col[j + 6], c7 = col[j + 7];
        ushort4 h0 = *(const ushort4*)(Hb + (size_t)c0 * 256);
        ushort4 h1 = *(const ushort4*)(Hb + (size_t)c1 * 256);
        ushort4 h2 = *(const ushort4*)(Hb + (size_t)c2 * 256);
        ushort4 h3 = *(const ushort4*)(Hb + (size_t)c3 * 256);
        ushort4 h4 = *(const ushort4*)(Hb + (size_t)c4 * 256);
        ushort4 h5 = *(const ushort4*)(Hb + (size_t)c5 * 256);
        ushort4 h6 = *(const ushort4*)(Hb + (size_t)c6 * 256);
        ushort4 h7 = *(const ushort4*)(Hb + (size_t)c7 * 256);
        a0 += b2f(h0.x) + b2f(h1.x) + b2f(h2.x) + b2f(h3.x)
            + b2f(h4.x) + b2f(h5.x) + b2f(h6.x) + b2f(h7.x);
        a1 += b2f(h0.y) + b2f(h1.y) + b2f(h2.y) + b2f(h3.y)
            + b2f(h4.y) + b2f(h5.y) + b2f(h6.y) + b2f(h7.y);
        a2 += b2f(h0.z) + b2f(h1.z) + b2f(h2.z) + b2f(h3.z)
            + b2f(h4.z) + b2f(h5.z) + b2f(h6.z) + b2f(h7.z);
        a3 += b2f(h0.w) + b2f(h1.w) + b2f(h2.w) + b2f(h3.w)
            + b2f(h4.w) + b2f(h5.w) + b2f(h6.w) + b2f(h7.w);
    }
    for (; j + 3 < e; j += 4) {
        int c0 = col[j], c1 = col[j + 1], c2 = col[j + 2], c3 = col[j + 3];
        ushort4 h0 = *(const ushort4*)(Hb + (size_t)c0 * 256);
        ushort4 h1 = *(const ushort4*)(Hb + (size_t)c1 * 256);
        ushort4 h2 = *(const ushort4*)(Hb + (size_t)c2 * 256);
        ushort4 h3 = *(const ushort4*)(Hb + (size_t)c3 * 256);
        a0 += b2f(h0.x) + b2f(h1.x) + b2f(h2.x) + b2f(h3.x);
        a1 += b2f(h0.y) + b2f(h1.y) + b2f(h2.y) + b2f(h3.y);
        a2 += b2f(h0.z) + b2f(h1.z) + b2f(h2.z) + b2f(h3.z);
        a3 += b2f(h0.w) + b2f(h1.w) + b2f(h2.w) + b2f(h3.w);
    }
    for (; j < e; j++) {
        int c = col[j];
        ushort4 h = *(const ushort4*)(Hb + (size_t)c * 256);
        a0 += b2f(h.x); a1 += b2f(h.y); a2 += b2f(h.z); a3 += b2f(h.w);
    }
    float v0 = fmaxf(b2f(xv.x) + a0 * inv, 0.0f);
    float v1 = fmaxf(b2f(xv.y) + a1 * inv, 0.0f);
    float v2 = fmaxf(b2f(xv.z) + a2 * inv, 0.0f);
    float v3 = fmaxf(b2f(xv.w) + a3 * inv, 0.0f);
    ushort4 o;
    o.x = f2b(v0); o.y = f2b(v1); o.z = f2b(v2); o.w = f2b(v3);
    *(ushort4*)xp = o;
    if (DOT) {
        float d = v0 * wv4.x + v1 * wv4.y + v2 * wv4.z + v3 * wv4.w;
        #pragma unroll
        for (int off = 32; off > 0; off >>= 1) d += __shfl_down(d, off);
        if (lane == 0) dotbuf[n] = d;
    }
}

// ---------------------------------------------------------------- pool reduce + head
__global__ void out_init_k(float* __restrict__ out, const float* __restrict__ headb) {
    int i = threadIdx.x;
    if (i < G_GRAPH * S_SAMP) out[i] = headb[0];
}

__global__ __launch_bounds__(256) void reduce_k(const float* __restrict__ dotbuf,
                                                const int* __restrict__ batch,
                                                float* __restrict__ out, int s) {
    __shared__ float part[G_GRAPH];
    if (threadIdx.x < G_GRAPH) part[threadIdx.x] = 0.0f;
    __syncthreads();
    for (int i = blockIdx.x * 256 + threadIdx.x; i < N_NODES; i += gridDim.x * 256)
        atomicAdd(&part[batch[i]], dotbuf[i]);
    __syncthreads();
    if (threadIdx.x < G_GRAPH)
        atomicAdd(&out[threadIdx.x * S_SAMP + s], part[threadIdx.x]);
}

// ---------------------------------------------------------------- launch
extern "C" void kernel_launch(void* const* d_in, const int* in_sizes, int n_in,
                              void* d_out, int out_size, void* d_ws, size_t ws_size,
                              hipStream_t stream) {
    const float* x_feat      = (const float*)d_in[0];
    const float* dim_feat    = (const float*)d_in[1];
    const float* layout_feat = (const float*)d_in[2];
    const float* tile_feat   = (const float*)d_in[3];
    const float* opemb       = (const float*)d_in[4];
    const float* preW        = (const float*)d_in[5];
    const float* preb        = (const float*)d_in[6];
    const float* convWl      = (const float*)d_in[7];
    const float* convWr      = (const float*)d_in[8];
    const float* convb       = (const float*)d_in[9];
    const float* revWl       = (const float*)d_in[10];
    const float* revWr       = (const float*)d_in[11];
    const float* revb        = (const float*)d_in[12];
    const float* headW       = (const float*)d_in[13];
    const float* headb       = (const float*)d_in[14];
    const int*   node_opcode = (const int*)d_in[15];
    const int*   batch       = (const int*)d_in[16];
    const int*   edge_index  = (const int*)d_in[17];
    float* out = (float*)d_out;

    char* ws = (char*)d_ws;
    size_t off = 0;
    auto alloc = [&](size_t nbytes) {
        char* p = ws + off;
        off += (nbytes + 255) & ~(size_t)255;
        return p;
    };
    u16* XA    = (u16*)alloc((size_t)NPAD * 256 * 2);      // 51.25 MB
    u16* XB    = (u16*)alloc((size_t)NPAD * 256 * 2);
    u16* XbH   = (u16*)alloc((size_t)NPAD * 256 * 2);      // base features, reused as H
    u16* Xmid  = (u16*)alloc((size_t)NPAD * 256 * 2);      // s-invariant pre-act (+preb)
    u16* Wt    = (u16*)alloc((size_t)NLAYER * 512 * 256 * 2);
    u16* preWt = (u16*)alloc((size_t)256 * KBASE * 2);
    float* bcat   = (float*)alloc(NLAYER * 512 * 4);
    float* tvec   = (float*)alloc(G_GRAPH * S_SAMP * 256 * 4);
    float* dotbuf = (float*)alloc((size_t)N_NODES * 4);
    int* degF  = (int*)alloc(N_NODES * 4);
    int* degR  = (int*)alloc(N_NODES * 4);
    int* rpF   = (int*)alloc((N_NODES + 1) * 4);
    int* rpR   = (int*)alloc((N_NODES + 1) * 4);
    int* curF  = (int*)alloc(N_NODES * 4);
    int* curR  = (int*)alloc(N_NODES * 4);
    int* colF  = (int*)alloc(E_EDGES * 4);
    int* colR  = (int*)alloc(E_EDGES * 4);
    int* bsum  = (int*)alloc(2 * NB1 * 4);
    float* invF = (float*)alloc(N_NODES * 4);
    float* invR = (float*)alloc(N_NODES * 4);

    hipMemsetAsync(degF, 0, N_NODES * 4, stream);
    hipMemsetAsync(degR, 0, N_NODES * 4, stream);

    pack_w_k<<<(NLAYER * 512 * 256 + 255) / 256, 256, 0, stream>>>(
        convWl, revWl, convWr, revWr, convb, revb, Wt, bcat);
    pack_pre_k<<<(256 * KBASE + 255) / 256, 256, 0, stream>>>(preW, preWt);
    tvec_k<<<(G_GRAPH * S_SAMP * 256 + 255) / 256, 256, 0, stream>>>(
        tile_feat, preW, tvec);
    deg_k<<<(E_EDGES + 255) / 256, 256, 0, stream>>>(edge_index, degF, degR);
    scan1_k<<<dim3(NB1, 2), 1024, 0, stream>>>(degF, degR, rpF, rpR, bsum);
    scan2_k<<<1, 256, 0, stream>>>(bsum, rpF, rpR);
    scan3_k<<<dim3(NB1, 2), 1024, 0, stream>>>(bsum, rpF, rpR);
    inv_cursor_k<<<(N_NODES + 255) / 256, 256, 0, stream>>>(
        degF, degR, rpF, rpR, invF, invR, curF, curR);
    fill_k<<<(E_EDGES + 255) / 256, 256, 0, stream>>>(edge_index, curF, curR, colF, colR);
    out_init_k<<<1, 64, 0, stream>>>(out, headb);

    // s-invariant: base features + base GEMM (preb folded as bias, no relu)
    build_base_k<<<(N_NODES * 64 + 255) / 256, 256, 0, stream>>>(
        x_feat, dim_feat, opemb, node_opcode, XbH);
    mmB_k<false, 2, 2><<<NG128 * 8 * 2, 256, 0, stream>>>(
        XbH, preWt, preb, Xmid, Xmid, N_NODES);

    const int gridL   = NG128 * 8 * 4;   // 3136
    const int gridAgg = (N_NODES * 64 + 255) / 256;

    for (int s = 0; s < S_SAMP; s++) {
        // X0 = relu(Xmid + lay_s @ Wlay + tvec[batch, s])
        pre_fix_k<<<2048, 256, 0, stream>>>(
            Xmid, layout_feat, preW, tvec, batch, s, XA);

        u16* ins[NLAYER]  = {XA, XB, XA, XB};
        u16* outs[NLAYER] = {XB, XA, XB, XA};
        for (int l = 0; l < NLAYER; l++) {
            // fused: [P | H] = x~ @ [Wr_cat | Wl_cat] + [b_cat | 0]; K=256 = 2 chunks
            mmB_k<false, 2, 4><<<gridL, 256, 0, stream>>>(
                ins[l], Wt + (size_t)l * 512 * 256, bcat + (size_t)l * 512,
                outs[l], XbH, N_NODES);
            if (l < 2) {
                agg_k<false><<<gridAgg, 256, 0, stream>>>(
                    rpF, colF, rpR, colR, invF, invR, XbH, outs[l],
                    nullptr, nullptr);
            } else {
                agg_k<true><<<gridAgg, 256, 0, stream>>>(
                    rpF, colF, rpR, colR, invF, invR, XbH, outs[l],
                    headW + (l == 2 ? 0 : 256), dotbuf);
                reduce_k<<<128, 256, 0, stream>>>(dotbuf, batch, out, s);
            }
        }
    }
}

// Round 7
// 1274.263 us; speedup vs baseline: 1.0262x; 1.0262x over previous
//
#include <hip/hip_runtime.h>
#include <hip/hip_bf16.h>

#define N_NODES 100000
#define S_SAMP 2
#define G_GRAPH 8
#define E_EDGES 400000
#define NLAYER 4
#define IN_CH 265
#define KBASE 256                       // s-invariant features: 223 padded to 256
#define MT128 ((N_NODES + 127) / 128)   // 782 row tiles (128 rows)
#define NPAD (MT128 * 128)              // 100096 padded rows
#define NG128 ((MT128 + 7) / 8)         // 98 groups -> 8 XCDs
#define NB1 ((N_NODES + 1023) / 1024)   // 98 scan blocks

typedef unsigned short u16;
typedef unsigned int u32;
typedef short bf16x8 __attribute__((ext_vector_type(8)));
typedef float f32x4 __attribute__((ext_vector_type(4)));

__device__ __forceinline__ float b2f(u16 u) {
    union { u32 i; float f; } x; x.i = ((u32)u) << 16; return x.f;
}
__device__ __forceinline__ u16 f2b(float f) {
    __hip_bfloat16 h = __float2bfloat16(f);
    return *reinterpret_cast<u16*>(&h);
}

// async global->LDS, 16B per lane; lds dest = wave-uniform base + lane*16
__device__ __forceinline__ void gl_lds16(const u16* g, u16* l) {
    __builtin_amdgcn_global_load_lds(
        (const __attribute__((address_space(1))) void*)g,
        (__attribute__((address_space(3))) void*)l, 16, 0, 0);
}

// ---------------------------------------------------------------- base features (s-invariant)
// xb[n][256] = [x(53)|op(32)|dim(138)|pad(33)]; 64 threads/node, ushort4 stores
__global__ __launch_bounds__(256) void build_base_k(const float* __restrict__ xf,
                                                    const float* __restrict__ dimf,
                                                    const float* __restrict__ opemb,
                                                    const int* __restrict__ opcode,
                                                    u16* __restrict__ xb) {
    int item = blockIdx.x * blockDim.x + threadIdx.x;
    int n = item >> 6;
    if (n >= N_NODES) return;
    int base = (item & 63) * 4;
    int opc = opcode[n];
    ushort4 o;
    u16* op = &o.x;
    #pragma unroll
    for (int u = 0; u < 4; u++) {
        int c = base + u;
        float v = 0.0f;
        if (c < 53)       v = xf[(size_t)n * 53 + c];
        else if (c < 85)  v = opemb[opc * 32 + (c - 53)];
        else if (c < 223) v = dimf[(size_t)n * 138 + (c - 85)];
        op[u] = f2b(v);
    }
    *(ushort4*)(xb + (size_t)n * KBASE + base) = o;
}

// ---------------------------------------------------------------- weight packing
// Wt: [L][512][256] bf16 transposed.  col<256 -> Wr_cat (P), col>=256 -> Wl_cat (H).
__global__ void pack_w_k(const float* __restrict__ cWl, const float* __restrict__ rWl,
                         const float* __restrict__ cWr, const float* __restrict__ rWr,
                         const float* __restrict__ cb,  const float* __restrict__ rb,
                         u16* __restrict__ Wt, float* __restrict__ bcat) {
    int idx = blockIdx.x * blockDim.x + threadIdx.x;
    if (idx < NLAYER * 512 * 256) {
        int l = idx >> 17;
        int r = idx & 131071;
        int j = r >> 8;
        int k = r & 255;
        int jj = j & 255;
        int half = j >> 8;
        int sub = jj >> 7;
        int col = jj & 127;
        const float* src = half ? (sub ? rWl : cWl) : (sub ? rWr : cWr);
        Wt[idx] = f2b(src[((size_t)l * 256 + k) * 128 + col]);
    }
    if (idx < NLAYER * 512) {
        int l = idx >> 9;
        int j = idx & 511;
        float v = 0.0f;
        if (j < 256) v = (j < 128) ? cb[l * 128 + j] : rb[l * 128 + (j - 128)];
        bcat[idx] = v;
    }
}

// preWt [256 out][256 k] transposed; only k<223 (base features), rest zero
__global__ void pack_pre_k(const float* __restrict__ preW, u16* __restrict__ preWt) {
    int idx = blockIdx.x * blockDim.x + threadIdx.x;
    if (idx >= 256 * KBASE) return;
    int j = idx >> 8;
    int k = idx & 255;
    preWt[idx] = (k < 223) ? f2b(preW[(size_t)k * 256 + j]) : (u16)0;
}

// layB [S][NPAD][32] bf16: cols 0..23 = layout_feat[n][s][:], 24..31 = 0
__global__ void pack_lay_k(const float* __restrict__ layf, u16* __restrict__ layB) {
    int idx = blockIdx.x * blockDim.x + threadIdx.x;
    if (idx >= N_NODES * 8) return;
    int n = idx >> 3;
    int q = idx & 7;
    #pragma unroll
    for (int s = 0; s < S_SAMP; s++) {
        ushort4 o;
        u16* op = &o.x;
        #pragma unroll
        for (int u = 0; u < 4; u++) {
            int c = q * 4 + u;
            op[u] = (c < 24) ? f2b(layf[((size_t)n * S_SAMP + s) * 24 + c]) : (u16)0;
        }
        *(ushort4*)(layB + ((size_t)s * NPAD + n) * 32 + q * 4) = o;
    }
}

// Wlay_t [256 out][32 k] bf16 from preW rows 223..246 (transposed), rest 0
__global__ void pack_wlay_k(const float* __restrict__ preW, u16* __restrict__ Wlt) {
    int idx = blockIdx.x * blockDim.x + threadIdx.x;
    if (idx >= 256 * 32) return;
    int j = idx >> 5;
    int k = idx & 31;
    Wlt[idx] = (k < 24) ? f2b(preW[(size_t)(223 + k) * 256 + j]) : (u16)0;
}

// tvec[g][s][c] = sum_k tile_feat[g][s][k] * preW[247+k][c]  (16 x 256, fp32)
__global__ void tvec_k(const float* __restrict__ tilef, const float* __restrict__ preW,
                       float* __restrict__ tvec) {
    int idx = blockIdx.x * blockDim.x + threadIdx.x;
    if (idx >= G_GRAPH * S_SAMP * 256) return;
    int c = idx & 255;
    int gs = idx >> 8;
    float a = 0.0f;
    #pragma unroll
    for (int k = 0; k < 18; k++)
        a += tilef[gs * 18 + k] * preW[(size_t)(247 + k) * 256 + c];
    tvec[idx] = a;
}

// ---------------------------------------------------------------- degrees + CSR
__global__ void deg_k(const int* __restrict__ ei, int* __restrict__ degF,
                      int* __restrict__ degR) {
    int e = blockIdx.x * blockDim.x + threadIdx.x;
    if (e < E_EDGES) {
        atomicAdd(&degF[ei[E_EDGES + e]], 1);
        atomicAdd(&degR[ei[e]], 1);
    }
}

__global__ __launch_bounds__(1024) void scan1_k(const int* __restrict__ degF,
                                                const int* __restrict__ degR,
                                                int* __restrict__ rpF,
                                                int* __restrict__ rpR,
                                                int* __restrict__ bsum) {
    const int* deg = blockIdx.y ? degR : degF;
    int* rp = blockIdx.y ? rpR : rpF;
    __shared__ int buf[1024];
    int i = blockIdx.x * 1024 + threadIdx.x;
    int v = (i < N_NODES) ? deg[i] : 0;
    buf[threadIdx.x] = v;
    __syncthreads();
    for (int off = 1; off < 1024; off <<= 1) {
        int t = (threadIdx.x >= off) ? buf[threadIdx.x - off] : 0;
        __syncthreads();
        buf[threadIdx.x] += t;
        __syncthreads();
    }
    if (i < N_NODES) rp[i] = buf[threadIdx.x] - v;
    if (threadIdx.x == 1023) bsum[blockIdx.y * NB1 + blockIdx.x] = buf[1023];
}

__global__ __launch_bounds__(256) void scan2_k(int* __restrict__ bsum,
                                               int* __restrict__ rpF,
                                               int* __restrict__ rpR) {
    __shared__ int buf[2][128];
    int half = threadIdx.x >> 7;
    int t = threadIdx.x & 127;
    int v = (t < NB1) ? bsum[half * NB1 + t] : 0;
    buf[half][t] = v;
    __syncthreads();
    for (int off = 1; off < 128; off <<= 1) {
        int x = (t >= off) ? buf[half][t - off] : 0;
        __syncthreads();
        buf[half][t] += x;
        __syncthreads();
    }
    if (t < NB1) bsum[half * NB1 + t] = buf[half][t] - v;
    if (t == NB1) (half ? rpR : rpF)[N_NODES] = buf[half][NB1 - 1];
}

__global__ void scan3_k(const int* __restrict__ bsum, int* __restrict__ rpF,
                        int* __restrict__ rpR) {
    int* rp = blockIdx.y ? rpR : rpF;
    int i = blockIdx.x * 1024 + threadIdx.x;
    if (i < N_NODES) rp[i] += bsum[blockIdx.y * NB1 + blockIdx.x];
}

__global__ void inv_cursor_k(const int* __restrict__ degF, const int* __restrict__ degR,
                             const int* __restrict__ rpF, const int* __restrict__ rpR,
                             float* __restrict__ invF, float* __restrict__ invR,
                             int* __restrict__ curF, int* __restrict__ curR) {
    int i = blockIdx.x * blockDim.x + threadIdx.x;
    if (i < N_NODES) {
        invF[i] = 1.0f / fmaxf((float)degF[i], 1.0f);
        invR[i] = 1.0f / fmaxf((float)degR[i], 1.0f);
        curF[i] = rpF[i];
        curR[i] = rpR[i];
    }
}

__global__ void fill_k(const int* __restrict__ ei, int* __restrict__ curF,
                       int* __restrict__ curR, int* __restrict__ colF,
                       int* __restrict__ colR) {
    int e = blockIdx.x * blockDim.x + threadIdx.x;
    if (e < E_EDGES) {
        int s = ei[e], t = ei[E_EDGES + e];
        colF[atomicAdd(&curF[t], 1)] = s;
        colR[atomicAdd(&curR[s], 1)] = t;
    }
}

// ---------------------------------------------------------------- MFMA GEMM (128x64 tile, DMA-staged)
// ROUND-4/5 VERIFIED CONFIG (61.5 us/layer-dispatch): K-chunk 128,
// single-buffered 48 KB LDS, 3 blocks/CU. Round-2 dbuf (74) and round-6
// 128x128 tile (+18 total) both REGRESSED -- keep this one.
// C^T epilogue: swapped MFMA operands -> 4 consecutive C-cols per f32x4
// -> ushort4 stores. Global col<256 -> C0 (+bias), else C1.
// XCD swizzle: bid = g*(8*COLT)+c*8+x.
template <bool RELU_OUT, int NCHUNK, int COLT>
__global__ __launch_bounds__(256) void mmB_k(const u16* __restrict__ A,
                                             const u16* __restrict__ Bt,
                                             const float* __restrict__ bias,
                                             u16* __restrict__ C0,
                                             u16* __restrict__ C1,
                                             int M) {
    __shared__ u16 As[128 * 128];    // 32 KB
    __shared__ u16 Bs[64 * 128];     // 16 KB
    constexpr int K = NCHUNK * 128;

    int bid = blockIdx.x;
    int x = bid & 7;
    int q = bid >> 3;
    int c = q % COLT;
    int g = q / COLT;
    int rowTile = g * 8 + x;
    if (rowTile >= MT128) return;
    int rowBase = rowTile * 128;
    int colBase = c * 64;

    int tid = threadIdx.x;
    int wv = tid >> 6;
    int lane = tid & 63;
    int quad = lane >> 4;
    int l16 = lane & 15;
    int rsub = lane >> 4;
    int sl = lane & 15;

    f32x4 acc[2][4] = {};

    for (int ci = 0; ci < NCHUNK; ci++) {
        int k0 = ci * 128;
        // A: wave wv stages rows [wv*32, wv*32+32): 8 DMA instrs x 4 rows
        #pragma unroll
        for (int i = 0; i < 8; i++) {
            int r = wv * 32 + 4 * i + rsub;
            int ch = sl ^ (r & 15);
            gl_lds16(A + (size_t)(rowBase + r) * K + k0 + ch * 8,
                     As + (wv * 32 + 4 * i) * 128);
        }
        // B: wave wv stages rows [wv*16, wv*16+16): 4 DMA instrs
        #pragma unroll
        for (int i = 0; i < 4; i++) {
            int r = wv * 16 + 4 * i + rsub;
            int ch = sl ^ (r & 15);
            gl_lds16(Bt + (size_t)(colBase + r) * K + k0 + ch * 8,
                     Bs + (wv * 16 + 4 * i) * 128);
        }
        __syncthreads();
        #pragma unroll
        for (int ks = 0; ks < 4; ks++) {
            int ca = ks * 4 + quad;
            bf16x8 af[2];
            #pragma unroll
            for (int rf = 0; rf < 2; rf++) {
                int ra = wv * 32 + rf * 16 + l16;
                af[rf] = *(const bf16x8*)(As + ra * 128 + (ca ^ (ra & 15)) * 8);
            }
            #pragma unroll
            for (int cf = 0; cf < 4; cf++) {
                int rb = cf * 16 + l16;
                bf16x8 bf = *(const bf16x8*)(Bs + rb * 128 + (ca ^ (rb & 15)) * 8);
                // swapped operands: acc = (A.B)^T fragment (round-4, verified)
                acc[0][cf] = __builtin_amdgcn_mfma_f32_16x16x32_bf16(bf, af[0], acc[0][cf], 0, 0, 0);
                acc[1][cf] = __builtin_amdgcn_mfma_f32_16x16x32_bf16(bf, af[1], acc[1][cf], 0, 0, 0);
            }
        }
        if (ci + 1 < NCHUNK) __syncthreads();
    }

    // epilogue (C^T frag): C-row = l16, C-col = quad*4 + r (4 consecutive cols)
    u16* dst = (colBase < 256) ? C0 : C1;
    int cb = colBase & 255;
    #pragma unroll
    for (int rf = 0; rf < 2; rf++) {
        int row = rowBase + wv * 32 + rf * 16 + l16;
        if (row < M) {
            #pragma unroll
            for (int cf = 0; cf < 4; cf++) {
                int colr = cf * 16 + quad * 4;
                float4 bv4 = *(const float4*)(bias + colBase + colr);
                float v0 = acc[rf][cf][0] + bv4.x;
                float v1 = acc[rf][cf][1] + bv4.y;
                float v2 = acc[rf][cf][2] + bv4.z;
                float v3 = acc[rf][cf][3] + bv4.w;
                if (RELU_OUT) {
                    v0 = fmaxf(v0, 0.0f); v1 = fmaxf(v1, 0.0f);
                    v2 = fmaxf(v2, 0.0f); v3 = fmaxf(v3, 0.0f);
                }
                ushort4 o;
                o.x = f2b(v0); o.y = f2b(v1); o.z = f2b(v2); o.w = f2b(v3);
                *(ushort4*)(dst + (size_t)row * 256 + cb + colr) = o;
            }
        }
    }
}

// ---------------------------------------------------------------- pre-layer fixup as K=32 GEMM
// ROUND-7: pre_fix was latency-bound at ~64us across 3 VALU implementations.
// It IS a GEMM: X0 = relu(Xmid + lay_s(Nx24) @ Wlay(24x256) + tvec[batch]).
// K padded to 32 -> ONE mfma_16x16x32 per fragment. 128x128 tile, 16 KB LDS,
// 4 DMA + 16 MFMA per wave; C^T epilogue fuses Xmid-add + tvec[batch[row]]
// + relu. Pure streaming: ~6.4+50 MB read, 50 MB write -> ~22-28us target.
__global__ __launch_bounds__(256) void mmFix_k(const u16* __restrict__ layB,
                                               const u16* __restrict__ Wlt,
                                               const u16* __restrict__ Xmid,
                                               const float* __restrict__ tvec,
                                               const int* __restrict__ batch,
                                               int s, u16* __restrict__ X0) {
    __shared__ u16 As[128 * 32];   // 8 KB
    __shared__ u16 Bs[128 * 32];   // 8 KB

    int bid = blockIdx.x;
    int x = bid & 7;
    int q = bid >> 3;
    int c = q & 1;        // COLT = 2
    int g = q >> 1;
    int rowTile = g * 8 + x;
    if (rowTile >= MT128) return;
    int rowBase = rowTile * 128;
    int colBase = c * 128;

    int tid = threadIdx.x;
    int wv = tid >> 6;
    int lane = tid & 63;
    int quad = lane >> 4;
    int l16 = lane & 15;
    int r16 = lane >> 2;   // 0..15 row within 16-row DMA group
    int sl = lane & 3;     // 16B slot 0..3 within 64B row

    // stage A rows [wv*32, wv*32+32): 2 DMA x 16 rows (rows beyond N read
    // pad garbage; epilogue guards row<N so it is never consumed)
    #pragma unroll
    for (int i = 0; i < 2; i++) {
        int r = wv * 32 + 16 * i + r16;
        int ch = sl ^ (r & 3);
        gl_lds16(layB + (size_t)(rowBase + r) * 32 + ch * 8,
                 As + (wv * 32 + 16 * i) * 32);
    }
    // stage B (Wlay_t) rows [wv*32, wv*32+32) of the 128-col tile
    #pragma unroll
    for (int i = 0; i < 2; i++) {
        int r = wv * 32 + 16 * i + r16;
        int ch = sl ^ (r & 3);
        gl_lds16(Wlt + (size_t)(colBase + r) * 32 + ch * 8,
                 Bs + (wv * 32 + 16 * i) * 32);
    }
    __syncthreads();

    f32x4 acc[2][8] = {};
    bf16x8 af[2];
    #pragma unroll
    for (int rf = 0; rf < 2; rf++) {
        int ra = wv * 32 + rf * 16 + l16;
        af[rf] = *(const bf16x8*)(As + ra * 32 + (quad ^ (ra & 3)) * 8);
    }
    #pragma unroll
    for (int cf = 0; cf < 8; cf++) {
        int rb = cf * 16 + l16;
        bf16x8 bf = *(const bf16x8*)(Bs + rb * 32 + (quad ^ (rb & 3)) * 8);
        // swapped operands -> C^T fragments (round-4 verified convention)
        acc[0][cf] = __builtin_amdgcn_mfma_f32_16x16x32_bf16(bf, af[0], acc[0][cf], 0, 0, 0);
        acc[1][cf] = __builtin_amdgcn_mfma_f32_16x16x32_bf16(bf, af[1], acc[1][cf], 0, 0, 0);
    }

    // epilogue: row = rowBase + wv*32 + rf*16 + l16; col = colBase + cf*16 + quad*4 + r
    #pragma unroll
    for (int rf = 0; rf < 2; rf++) {
        int row = rowBase + wv * 32 + rf * 16 + l16;
        if (row < N_NODES) {
            int gg = batch[row];
            const float* tvb = tvec + ((size_t)gg * S_SAMP + s) * 256 + colBase;
            const u16* xm = Xmid + (size_t)row * 256 + colBase;
            u16* xo = X0 + (size_t)row * 256 + colBase;
            #pragma unroll
            for (int cf = 0; cf < 8; cf++) {
                int colr = cf * 16 + quad * 4;
                float4 t4 = *(const float4*)(tvb + colr);
                ushort4 m = *(const ushort4*)(xm + colr);
                ushort4 o;
                o.x = f2b(fmaxf(acc[rf][cf][0] + t4.x + b2f(m.x), 0.0f));
                o.y = f2b(fmaxf(acc[rf][cf][1] + t4.y + b2f(m.y), 0.0f));
                o.z = f2b(fmaxf(acc[rf][cf][2] + t4.z + b2f(m.z), 0.0f));
                o.w = f2b(fmaxf(acc[rf][cf][3] + t4.w + b2f(m.w), 0.0f));
                *(ushort4*)(xo + colr) = o;
            }
        }
    }
}

// ---------------------------------------------------------------- aggregation (CSR gather)
// One wave per node. Lanes 0-31: fwd half (H[.,0:128]); lanes 32-63: rev half.
// X := relu(X + inv*gather). If DOT: dotbuf[n] = X_new . w.
template <bool DOT>
__global__ __launch_bounds__(256) void agg_k(const int* __restrict__ rpF,
                                             const int* __restrict__ colF,
                                             const int* __restrict__ rpR,
                                             const int* __restrict__ colR,
                                             const float* __restrict__ invF,
                                             const float* __restrict__ invR,
                                             const u16* __restrict__ H,
                                             u16* __restrict__ Xn,
                                             const float* __restrict__ w,
                                             float* __restrict__ dotbuf) {
    int n = (blockIdx.x * blockDim.x + threadIdx.x) >> 6;
    if (n >= N_NODES) return;
    int lane = threadIdx.x & 63;
    int half = lane >> 5;
    int l32 = lane & 31;
    const int* rp  = half ? rpR : rpF;
    const int* col = half ? colR : colF;
    float inv = half ? invR[n] : invF[n];
    const u16* Hb = H + half * 128 + 4 * l32;

    // early loads: X row and head-w overlap the gather latency
    u16* xp = Xn + (size_t)n * 256 + 4 * lane;
    ushort4 xv = *(const ushort4*)xp;
    float4 wv4 = DOT ? *(const float4*)(w + 4 * lane) : float4{0, 0, 0, 0};

    float a0 = 0, a1 = 0, a2 = 0, a3 = 0;
    int b = rp[n], e = rp[n + 1];
    int j = b;
    for (; j + 7 < e; j += 8) {
        int c0 = col[j],     c1 = col[j + 1], c2 = col[j + 2], c3 = col[j + 3];
        int c4 = col[j + 4], c5 = col[j + 5], c6 = col[j + 6], c7 = col[j + 7];
        ushort4 h0 = *(const ushort4*)(Hb + (size_t)c0 * 256);
        ushort4 h1 = *(const ushort4*)(Hb + (size_t)c1 * 256);
        ushort4 h2 = *(const ushort4*)(Hb + (size_t)c2 * 256);
        ushort4 h3 = *(const ushort4*)(Hb + (size_t)c3 * 256);
        ushort4 h4 = *(const ushort4*)(Hb + (size_t)c4 * 256);
        ushort4 h5 = *(const ushort4*)(Hb + (size_t)c5 * 256);
        ushort4 h6 = *(const ushort4*)(Hb + (size_t)c6 * 256);
        ushort4 h7 = *(const ushort4*)(Hb + (size_t)c7 * 256);
        a0 += b2f(h0.x) + b2f(h1.x) + b2f(h2.x) + b2f(h3.x)
            + b2f(h4.x) + b2f(h5.x) + b2f(h6.x) + b2f(h7.x);
        a1 += b2f(h0.y) + b2f(h1.y) + b2f(h2.y) + b2f(h3.y)
            + b2f(h4.y) + b2f(h5.y) + b2f(h6.y) + b2f(h7.y);
        a2 += b2f(h0.z) + b2f(h1.z) + b2f(h2.z) + b2f(h3.z)
            + b2f(h4.z) + b2f(h5.z) + b2f(h6.z) + b2f(h7.z);
        a3 += b2f(h0.w) + b2f(h1.w) + b2f(h2.w) + b2f(h3.w)
            + b2f(h4.w) + b2f(h5.w) + b2f(h6.w) + b2f(h7.w);
    }
    for (; j + 3 < e; j += 4) {
        int c0 = col[j], c1 = col[j + 1], c2 = col[j + 2], c3 = col[j + 3];
        ushort4 h0 = *(const ushort4*)(Hb + (size_t)c0 * 256);
        ushort4 h1 = *(const ushort4*)(Hb + (size_t)c1 * 256);
        ushort4 h2 = *(const ushort4*)(Hb + (size_t)c2 * 256);
        ushort4 h3 = *(const ushort4*)(Hb + (size_t)c3 * 256);
        a0 += b2f(h0.x) + b2f(h1.x) + b2f(h2.x) + b2f(h3.x);
        a1 += b2f(h0.y) + b2f(h1.y) + b2f(h2.y) + b2f(h3.y);
        a2 += b2f(h0.z) + b2f(h1.z) + b2f(h2.z) + b2f(h3.z);
        a3 += b2f(h0.w) + b2f(h1.w) + b2f(h2.w) + b2f(h3.w);
    }
    for (; j < e; j++) {
        int c = col[j];
        ushort4 h = *(const ushort4*)(Hb + (size_t)c * 256);
        a0 += b2f(h.x); a1 += b2f(h.y); a2 += b2f(h.z); a3 += b2f(h.w);
    }
    float v0 = fmaxf(b2f(xv.x) + a0 * inv, 0.0f);
    float v1 = fmaxf(b2f(xv.y) + a1 * inv, 0.0f);
    float v2 = fmaxf(b2f(xv.z) + a2 * inv, 0.0f);
    float v3 = fmaxf(b2f(xv.w) + a3 * inv, 0.0f);
    ushort4 o;
    o.x = f2b(v0); o.y = f2b(v1); o.z = f2b(v2); o.w = f2b(v3);
    *(ushort4*)xp = o;
    if (DOT) {
        float d = v0 * wv4.x + v1 * wv4.y + v2 * wv4.z + v3 * wv4.w;
        #pragma unroll
        for (int off = 32; off > 0; off >>= 1) d += __shfl_down(d, off);
        if (lane == 0) dotbuf[n] = d;
    }
}

// ---------------------------------------------------------------- pool reduce + head
__global__ void out_init_k(float* __restrict__ out, const float* __restrict__ headb) {
    int i = threadIdx.x;
    if (i < G_GRAPH * S_SAMP) out[i] = headb[0];
}

__global__ __launch_bounds__(256) void reduce_k(const float* __restrict__ dotbuf,
                                                const int* __restrict__ batch,
                                                float* __restrict__ out, int s) {
    __shared__ float part[G_GRAPH];
    if (threadIdx.x < G_GRAPH) part[threadIdx.x] = 0.0f;
    __syncthreads();
    for (int i = blockIdx.x * 256 + threadIdx.x; i < N_NODES; i += gridDim.x * 256)
        atomicAdd(&part[batch[i]], dotbuf[i]);
    __syncthreads();
    if (threadIdx.x < G_GRAPH)
        atomicAdd(&out[threadIdx.x * S_SAMP + s], part[threadIdx.x]);
}

// ---------------------------------------------------------------- launch
extern "C" void kernel_launch(void* const* d_in, const int* in_sizes, int n_in,
                              void* d_out, int out_size, void* d_ws, size_t ws_size,
                              hipStream_t stream) {
    const float* x_feat      = (const float*)d_in[0];
    const float* dim_feat    = (const float*)d_in[1];
    const float* layout_feat = (const float*)d_in[2];
    const float* tile_feat   = (const float*)d_in[3];
    const float* opemb       = (const float*)d_in[4];
    const float* preW        = (const float*)d_in[5];
    const float* preb        = (const float*)d_in[6];
    const float* convWl      = (const float*)d_in[7];
    const float* convWr      = (const float*)d_in[8];
    const float* convb       = (const float*)d_in[9];
    const float* revWl       = (const float*)d_in[10];
    const float* revWr       = (const float*)d_in[11];
    const float* revb        = (const float*)d_in[12];
    const float* headW       = (const float*)d_in[13];
    const float* headb       = (const float*)d_in[14];
    const int*   node_opcode = (const int*)d_in[15];
    const int*   batch       = (const int*)d_in[16];
    const int*   edge_index  = (const int*)d_in[17];
    float* out = (float*)d_out;

    char* ws = (char*)d_ws;
    size_t off = 0;
    auto alloc = [&](size_t nbytes) {
        char* p = ws + off;
        off += (nbytes + 255) & ~(size_t)255;
        return p;
    };
    u16* XA    = (u16*)alloc((size_t)NPAD * 256 * 2);      // 51.25 MB
    u16* XB    = (u16*)alloc((size_t)NPAD * 256 * 2);
    u16* XbH   = (u16*)alloc((size_t)NPAD * 256 * 2);      // base features, reused as H
    u16* Xmid  = (u16*)alloc((size_t)NPAD * 256 * 2);      // s-invariant pre-act (+preb)
    u16* layB  = (u16*)alloc((size_t)S_SAMP * NPAD * 32 * 2);  // 12.8 MB
    u16* Wt    = (u16*)alloc((size_t)NLAYER * 512 * 256 * 2);
    u16* preWt = (u16*)alloc((size_t)256 * KBASE * 2);
    u16* Wlt   = (u16*)alloc((size_t)256 * 32 * 2);
    float* bcat   = (float*)alloc(NLAYER * 512 * 4);
    float* tvec   = (float*)alloc(G_GRAPH * S_SAMP * 256 * 4);
    float* dotbuf = (float*)alloc((size_t)N_NODES * 4);
    int* degF  = (int*)alloc(N_NODES * 4);
    int* degR  = (int*)alloc(N_NODES * 4);
    int* rpF   = (int*)alloc((N_NODES + 1) * 4);
    int* rpR   = (int*)alloc((N_NODES + 1) * 4);
    int* curF  = (int*)alloc(N_NODES * 4);
    int* curR  = (int*)alloc(N_NODES * 4);
    int* colF  = (int*)alloc(E_EDGES * 4);
    int* colR  = (int*)alloc(E_EDGES * 4);
    int* bsum  = (int*)alloc(2 * NB1 * 4);
    float* invF = (float*)alloc(N_NODES * 4);
    float* invR = (float*)alloc(N_NODES * 4);

    hipMemsetAsync(degF, 0, N_NODES * 4, stream);
    hipMemsetAsync(degR, 0, N_NODES * 4, stream);

    pack_w_k<<<(NLAYER * 512 * 256 + 255) / 256, 256, 0, stream>>>(
        convWl, revWl, convWr, revWr, convb, revb, Wt, bcat);
    pack_pre_k<<<(256 * KBASE + 255) / 256, 256, 0, stream>>>(preW, preWt);
    pack_lay_k<<<(N_NODES * 8 + 255) / 256, 256, 0, stream>>>(layout_feat, layB);
    pack_wlay_k<<<(256 * 32 + 255) / 256, 256, 0, stream>>>(preW, Wlt);
    tvec_k<<<(G_GRAPH * S_SAMP * 256 + 255) / 256, 256, 0, stream>>>(
        tile_feat, preW, tvec);
    deg_k<<<(E_EDGES + 255) / 256, 256, 0, stream>>>(edge_index, degF, degR);
    scan1_k<<<dim3(NB1, 2), 1024, 0, stream>>>(degF, degR, rpF, rpR, bsum);
    scan2_k<<<1, 256, 0, stream>>>(bsum, rpF, rpR);
    scan3_k<<<dim3(NB1, 2), 1024, 0, stream>>>(bsum, rpF, rpR);
    inv_cursor_k<<<(N_NODES + 255) / 256, 256, 0, stream>>>(
        degF, degR, rpF, rpR, invF, invR, curF, curR);
    fill_k<<<(E_EDGES + 255) / 256, 256, 0, stream>>>(edge_index, curF, curR, colF, colR);
    out_init_k<<<1, 64, 0, stream>>>(out, headb);

    // s-invariant: base features + base GEMM (preb folded as bias, no relu)
    build_base_k<<<(N_NODES * 64 + 255) / 256, 256, 0, stream>>>(
        x_feat, dim_feat, opemb, node_opcode, XbH);
    mmB_k<false, 2, 4><<<NG128 * 8 * 4, 256, 0, stream>>>(
        XbH, preWt, preb, Xmid, Xmid, N_NODES);

    const int gridL   = NG128 * 8 * 8;   // 6272
    const int gridFix = NG128 * 8 * 2;   // 1568
    const int gridAgg = (N_NODES * 64 + 255) / 256;

    for (int s = 0; s < S_SAMP; s++) {
        // X0 = relu(Xmid + lay_s @ Wlay + tvec[batch, s])  (K=32 MFMA GEMM)
        mmFix_k<<<gridFix, 256, 0, stream>>>(
            layB + (size_t)s * NPAD * 32, Wlt, Xmid, tvec, batch, s, XA);

        u16* ins[NLAYER]  = {XA, XB, XA, XB};
        u16* outs[NLAYER] = {XB, XA, XB, XA};
        for (int l = 0; l < NLAYER; l++) {
            // fused: [P | H] = x~ @ [Wr_cat | Wl_cat] + [b_cat | 0]; K=256 = 2 chunks
            mmB_k<false, 2, 8><<<gridL, 256, 0, stream>>>(
                ins[l], Wt + (size_t)l * 512 * 256, bcat + (size_t)l * 512,
                outs[l], XbH, N_NODES);
            if (l < 2) {
                agg_k<false><<<gridAgg, 256, 0, stream>>>(
                    rpF, colF, rpR, colR, invF, invR, XbH, outs[l],
                    nullptr, nullptr);
            } else {
                agg_k<true><<<gridAgg, 256, 0, stream>>>(
                    rpF, colF, rpR, colR, invF, invR, XbH, outs[l],
                    headW + (l == 2 ? 0 : 256), dotbuf);
                reduce_k<<<128, 256, 0, stream>>>(dotbuf, batch, out, s);
            }
        }
    }
}